// Round 10
// baseline (106.036 us; speedup 1.0000x reference)
//
#include <hip/hip_runtime.h>

#define HW 4096
#define CCH 256
#define MOFF 432
#define PTOT 32768
#define PDIM 68
#define PIMG (PDIM*PDIM)      // 4624 padded cells per group-plane (2-wide zero border)

typedef unsigned short u16;
typedef __attribute__((ext_vector_type(8))) short short8;
typedef __attribute__((ext_vector_type(8))) unsigned short u16x8;
typedef __attribute__((ext_vector_type(4))) unsigned short u16x4;
typedef __attribute__((ext_vector_type(4))) float f32x4;

__device__ __forceinline__ u16 f2b(float f){
  unsigned int u = __float_as_uint(f);
  unsigned int rounding = 0x7FFFu + ((u >> 16) & 1u);
  return (u16)((u + rounding) >> 16);
}
__device__ __forceinline__ float b2f(u16 s){
  return __uint_as_float(((unsigned int)s) << 16);
}

// ---------------------------------------------------------------------------
// k_prep: ALL independent prep in ONE launch (unchanged from R8/R9).
// ---------------------------------------------------------------------------
__global__ __launch_bounds__(256) void k_prep(const float* __restrict__ x,
    const float* __restrict__ w1, const float* __restrict__ w2,
    const float* __restrict__ woff, const float* __restrict__ b1,
    const float* __restrict__ boff,
    const float* __restrict__ gamma, const float* __restrict__ beta,
    const float* __restrict__ mean, const float* __restrict__ var,
    u16* __restrict__ xT, u16* __restrict__ wb_big, u16* __restrict__ wb2,
    float* __restrict__ bnA, float* __restrict__ bnB,
    float* __restrict__ bcomb, u16* __restrict__ h1p){
  __shared__ float tile[64][65];
  const int r = blockIdx.x, t = threadIdx.x;
  if (r < 2048){
    const int pb = (r & 63) * 64, cb = ((r >> 6) & 3) * 64, b = r >> 8;
    const float* src = x + ((size_t)(b * CCH + cb)) * HW + pb;
    #pragma unroll
    for (int pass = 0; pass < 4; ++pass){
      int c_l = pass * 16 + (t >> 4);
      int pq = (t & 15) * 4;
      float4 v = *reinterpret_cast<const float4*>(&src[(size_t)c_l * HW + pq]);
      tile[pq + 0][c_l] = v.x; tile[pq + 1][c_l] = v.y;
      tile[pq + 2][c_l] = v.z; tile[pq + 3][c_l] = v.w;
    }
    __syncthreads();
    #pragma unroll
    for (int pass = 0; pass < 4; ++pass){
      int p_l = pass * 16 + (t >> 4);
      int cq = (t & 15) * 4;
      u16x4 o4;
      #pragma unroll
      for (int j = 0; j < 4; ++j) o4[j] = f2b(tile[p_l][cq + j]);
      *reinterpret_cast<u16x4*>(&xT[((size_t)b * HW + pb + p_l) * CCH + cb + cq]) = o4;
    }
  }
  else if (r < 2304){ int o = r - 2048; wb_big[o*256 + t] = f2b(w1[o*256 + t]); }
  else if (r < 2384){ wb_big[(688 + (r - 2304)) * 256 + t] = 0; }
  else if (r < 2640){ int o = r - 2384; wb2[o*256 + t] = f2b(w2[o*256 + t]); }
  else if (r == 2640){
    if (t < 256){
      float sc = gamma[t] * rsqrtf(var[t] + 1e-5f);
      bnA[t] = sc;
      bnB[t] = beta[t] - mean[t] * sc;
    }
  } else if (r < 3169){
    int n = (r - 2641) * 128 + (t >> 1);   // border cell index
    int seg = t & 1;
    int plane = n / 528, m = n % 528;
    int row, col;
    if (m < 136){ row = m / 68; col = m % 68; }
    else if (m < 272){ int mm = m - 136; row = 66 + mm / 68; col = mm % 68; }
    else { int mm = m - 272; row = 2 + (mm >> 2); int c4 = mm & 3; col = (c4 & 1) + 66 * (c4 >> 1); }
    u16x8 z = {};
    *reinterpret_cast<u16x8*>(&h1p[((size_t)plane * PIMG + row * PDIM + col) * 16 + seg * 8]) = z;
  } else {
    float* wr_ = &tile[0][0];
    float* pb  = wr_ + 256;
    const int j = r - 3169;
    wr_[t] = woff[j * 256 + t];
    __syncthreads();
    float s = 0.f;
    #pragma unroll 8
    for (int m = 0; m < 256; ++m) s += wr_[m] * w1[m * 256 + t];
    wb_big[(256 + j) * 256 + t] = f2b(s);
    pb[t] = wr_[t] * b1[t];
    __syncthreads();
    if (t == 0){
      float bs = boff[j];
      for (int m = 0; m < 256; ++m) bs += pb[m];
      bcomb[j] = bs;
    }
  }
}

// ---------------------------------------------------------------------------
// k_gemm_big: [h1 | om] = xT * wb_big^T. Tile 256x128, BK=64 (unchanged).
// ---------------------------------------------------------------------------
__global__ __launch_bounds__(256, 2) void k_gemm_big(const u16* __restrict__ A,
    const u16* __restrict__ Bw, const float* __restrict__ b1,
    const float* __restrict__ bcomb, u16* __restrict__ h1p,
    u16* __restrict__ om){
  __shared__ __align__(16) u16 smem[34816];   // 69632 B: max(As+Bs staging, C_l)
  u16* As = smem;                   // 256*72
  u16* Bs = smem + 256 * 72;        // 128*72

  const int bid = blockIdx.x;
  const int xcd = bid & 7, s = bid >> 3;
  const int row_local = s / 6, cblk = s % 6;
  const int tm = (row_local * 8 + xcd) * 256;
  const int tn = cblk * 128;

  const int t = threadIdx.x;
  const int lane = t & 63;
  const int wid = t >> 6;
  const int wr = wid >> 1, wc = wid & 1;

  f32x4 acc[8][4] = {};

  for (int kc = 0; kc < 256; kc += 64){
    #pragma unroll
    for (int i = 0; i < 8; ++i){
      int idx = t + i * 256;
      int row = idx >> 3, cq = idx & 7;
      *reinterpret_cast<u16x8*>(&As[row * 72 + cq * 8]) =
        *reinterpret_cast<const u16x8*>(&A[(size_t)(tm + row) * 256 + kc + cq * 8]);
    }
    #pragma unroll
    for (int i = 0; i < 4; ++i){
      int idx = t + i * 256;
      int row = idx >> 3, cq = idx & 7;
      *reinterpret_cast<u16x8*>(&Bs[row * 72 + cq * 8]) =
        *reinterpret_cast<const u16x8*>(&Bw[(size_t)(tn + row) * 256 + kc + cq * 8]);
    }
    __syncthreads();
    #pragma unroll
    for (int kk = 0; kk < 2; ++kk){
      short8 af[8], bf[4];
      #pragma unroll
      for (int m = 0; m < 8; ++m)
        af[m] = *reinterpret_cast<const short8*>(
          &As[(wr * 128 + m * 16 + (lane & 15)) * 72 + kk * 32 + (lane >> 4) * 8]);
      #pragma unroll
      for (int n = 0; n < 4; ++n)
        bf[n] = *reinterpret_cast<const short8*>(
          &Bs[(wc * 64 + n * 16 + (lane & 15)) * 72 + kk * 32 + (lane >> 4) * 8]);
      #pragma unroll
      for (int m = 0; m < 8; ++m)
        #pragma unroll
        for (int n = 0; n < 4; ++n)
          acc[m][n] = __builtin_amdgcn_mfma_f32_16x16x32_bf16(af[m], bf[n], acc[m][n], 0, 0, 0);
    }
    __syncthreads();
  }

  constexpr int CP = 136;
  u16* C_l = smem;
  #pragma unroll
  for (int n = 0; n < 4; ++n){
    int col = wc * 64 + n * 16 + (lane & 15);
    int o = tn + col;
    float bi = (o < 256) ? b1[o] : ((o - 256 < MOFF) ? bcomb[o - 256] : 0.f);
    #pragma unroll
    for (int m = 0; m < 8; ++m){
      int r0 = wr * 128 + m * 16 + ((lane >> 4) << 2);
      #pragma unroll
      for (int j = 0; j < 4; ++j)
        C_l[(r0 + j) * CP + col] = f2b(acc[m][n][j] + bi);
    }
  }
  __syncthreads();
  #pragma unroll
  for (int pass = 0; pass < 16; ++pass){
    int row = pass * 16 + (t >> 4);
    int sg = t & 15;
    int oc = tn + sg * 8;
    int p = tm + row;
    if (tn < 256){
      int bb = p >> 12, ii = (p >> 6) & 63, jj = p & 63;
      size_t dst = ((size_t)(bb * 16 + (oc >> 4)) * PIMG + (ii + 2) * PDIM + jj + 2) * 16 + (oc & 15);
      *reinterpret_cast<u16x8*>(&h1p[dst]) =
        *reinterpret_cast<const u16x8*>(&C_l[row * CP + sg * 8]);
    } else {
      int occ = oc - 256;
      if (occ + 8 <= MOFF)
        *reinterpret_cast<u16x8*>(&om[(size_t)p * MOFF + occ]) =
          *reinterpret_cast<const u16x8*>(&C_l[row * CP + sg * 8]);
    }
  }
}

// ---------------------------------------------------------------------------
// k_fuse: sample + conv2 + BN + SiLU in ONE kernel. 512 thr, tile M=64 px.
// Phase A (x8): stage om for 8 px; 4-lane units (px,g,q) gather-bilinear;
//   pair-reduce; write bf16 sample tile into A_lds (pitch 264, 2-way-free).
// Phase B: GEMM A_lds x wb2^T (K=256, BK=32), 8 waves 2x4, BN+SiLU epilogue,
//   fp32 NCHW stores. ydcn never touches HBM.
// ---------------------------------------------------------------------------
__global__ __launch_bounds__(512, 4) void k_fuse(const u16* __restrict__ h1p,
    const u16* __restrict__ om, const u16* __restrict__ Bw,
    const float* __restrict__ bnA, const float* __restrict__ bnB,
    float* __restrict__ out){
  __shared__ __align__(16) u16 A_lds[64 * 264];   // 33792 B sample tile
  __shared__ __align__(16) u16 scratch[10240];    // 20480 B: om-f32 | Bs
  float* oms = (float*)scratch;                   // 8*432 f32 = 13824 B
  u16* Bs = scratch;                              // 256*40 u16 = 20480 B

  const int t = threadIdx.x;
  const int tm = blockIdx.x * 64;
  const int b = tm >> 12;

  // ---- Phase A: sample 64 px in 8 chunks of 8 px ----
  const int px8 = t >> 6;              // 0..7
  const int g = (t >> 2) & 15;
  const int q = t & 3;
  const int xsel = q >> 1;
  const u16* plane = h1p + (size_t)(b * 16 + g) * PIMG * 16;

  for (int c8 = 0; c8 < 8; ++c8){
    {
      const u16* src = om + (size_t)(tm + c8 * 8) * MOFF;
      if (t < 432){
        u16x8 v = *reinterpret_cast<const u16x8*>(&src[t * 8]);
        float4 lo, hi;
        lo.x = b2f(v[0]); lo.y = b2f(v[1]); lo.z = b2f(v[2]); lo.w = b2f(v[3]);
        hi.x = b2f(v[4]); hi.y = b2f(v[5]); hi.z = b2f(v[6]); hi.w = b2f(v[7]);
        *reinterpret_cast<float4*>(&oms[t * 8]) = lo;
        *reinterpret_cast<float4*>(&oms[t * 8 + 4]) = hi;
      }
    }
    __syncthreads();

    const int lpx = c8 * 8 + px8;
    const int p = tm + lpx;
    const int hw = p & 4095;
    const int ic = hw >> 6, jc = hw & 63;
    const float* ob = &oms[px8 * MOFF + g * 27];
    const float fi = (float)ic, fj = (float)jc;
    const u16* lanebase = plane + q * 8;

    float acc[8] = {};
    #pragma unroll
    for (int k = 0; k < 9; ++k){
      float oh = ob[2 * k], ow = ob[2 * k + 1], m = ob[18 + k];
      float ph = fi + (float)(k / 3 - 1) + oh;
      float pw = fj + (float)(k % 3 - 1) + ow;
      float h0f = floorf(ph), w0f = floorf(pw);
      float ah = ph - h0f, aw = pw - w0f;
      int h0 = (int)h0f, w0 = (int)w0f;
      int hc = min(max(h0, -2), 64) + 2;
      int wc = min(max(w0, -2), 64) + 2;
      const u16* c0 = lanebase + ((hc * PDIM + wc) << 4);
      u16x8 tv = *reinterpret_cast<const u16x8*>(c0);
      u16x8 bv = *reinterpret_cast<const u16x8*>(c0 + PDIM * 16);
      float mh1 = m * ah, mh0 = m - mh1;
      float awq = xsel ? aw : (1.f - aw);
      float ct = mh0 * awq, cb = mh1 * awq;
      #pragma unroll
      for (int j = 0; j < 8; ++j)
        acc[j] += ct * b2f(tv[j]) + cb * b2f(bv[j]);
    }
    #pragma unroll
    for (int j = 0; j < 8; ++j)
      acc[j] += __shfl_xor(acc[j], 2, 64);
    if (q < 2){
      u16x8 o8;
      #pragma unroll
      for (int j = 0; j < 8; ++j) o8[j] = f2b(acc[j]);
      *reinterpret_cast<u16x8*>(&A_lds[lpx * 264 + g * 16 + q * 8]) = o8;
    }
    __syncthreads();
  }

  // ---- Phase B: GEMM 64x256 = A_lds * wb2^T ----
  const int lane = t & 63;
  const int wid = t >> 6;
  const int wr = wid >> 2, wc = wid & 3;   // 2x4 wave grid; wave tile 32x64

  f32x4 gacc[2][4] = {};

  for (int kc = 0; kc < 256; kc += 32){
    #pragma unroll
    for (int i = 0; i < 2; ++i){
      int idx = t + i * 512;
      int row = idx >> 2, cq = idx & 3;
      *reinterpret_cast<u16x8*>(&Bs[row * 40 + cq * 8]) =
        *reinterpret_cast<const u16x8*>(&Bw[(size_t)row * 256 + kc + cq * 8]);
    }
    __syncthreads();
    short8 af[2], bf[4];
    #pragma unroll
    for (int m = 0; m < 2; ++m)
      af[m] = *reinterpret_cast<const short8*>(
        &A_lds[(wr * 32 + m * 16 + (lane & 15)) * 264 + kc + (lane >> 4) * 8]);
    #pragma unroll
    for (int n = 0; n < 4; ++n)
      bf[n] = *reinterpret_cast<const short8*>(
        &Bs[(wc * 64 + n * 16 + (lane & 15)) * 40 + (lane >> 4) * 8]);
    #pragma unroll
    for (int m = 0; m < 2; ++m)
      #pragma unroll
      for (int n = 0; n < 4; ++n)
        gacc[m][n] = __builtin_amdgcn_mfma_f32_16x16x32_bf16(af[m], bf[n], gacc[m][n], 0, 0, 0);
    __syncthreads();
  }

  const int ploc = tm & 4095;
  #pragma unroll
  for (int n = 0; n < 4; ++n){
    int o = wc * 64 + n * 16 + (lane & 15);
    float sA = bnA[o], sB = bnB[o];
    #pragma unroll
    for (int m = 0; m < 2; ++m){
      int prow = wr * 32 + m * 16 + ((lane >> 4) << 2);
      f32x4 st;
      #pragma unroll
      for (int j = 0; j < 4; ++j){
        float y = gacc[m][n][j] * sA + sB;
        st[j] = y / (1.f + expf(-y));
      }
      *reinterpret_cast<f32x4*>(&out[((size_t)(b * 256 + o)) * HW + ploc + prow]) = st;
    }
  }
}

extern "C" void kernel_launch(void* const* d_in, const int* in_sizes, int n_in,
                              void* d_out, int out_size, void* d_ws, size_t ws_size,
                              hipStream_t stream) {
  const float* x     = (const float*)d_in[0];
  const float* w1    = (const float*)d_in[1];
  const float* b1    = (const float*)d_in[2];
  const float* woff  = (const float*)d_in[3];
  const float* boff  = (const float*)d_in[4];
  const float* w2    = (const float*)d_in[5];
  const float* gamma = (const float*)d_in[6];
  const float* beta  = (const float*)d_in[7];
  const float* mean  = (const float*)d_in[8];
  const float* var   = (const float*)d_in[9];
  float* out = (float*)d_out;
  (void)in_sizes; (void)n_in; (void)out_size; (void)ws_size;

  u16* h1p    = (u16*)d_ws;                               // 128 planes * 4624 * 32B = 18.9 MB
  u16* om     = h1p + (size_t)128 * PIMG * 16;            // 32768*432 = 28.3 MB
  u16* xT     = om + (size_t)PTOT * MOFF;                 // 32768*256 = 16.8 MB
  u16* wb_big = xT + (size_t)PTOT * CCH;                  // 768*256 bf16
  u16* wb2    = wb_big + 768 * 256;                       // 256*256
  float* bnA  = (float*)(wb2 + 256 * 256);
  float* bnB  = bnA + 256;
  float* bcomb = bnB + 256;                               // 432 f32

  dim3 blk(256);
  k_prep<<<dim3(3601), blk, 0, stream>>>(x, w1, w2, woff, b1, boff,
                                         gamma, beta, mean, var,
                                         xT, wb_big, wb2, bnA, bnB, bcomb, h1p);
  k_gemm_big<<<dim3(768), blk, 0, stream>>>(xT, wb_big, b1, bcomb, h1p, om);
  k_fuse<<<dim3(PTOT / 64), dim3(512), 0, stream>>>(h1p, om, wb2, bnA, bnB, out);
}

// Round 11
// 98.829 us; speedup vs baseline: 1.0729x; 1.0729x over previous
//
#include <hip/hip_runtime.h>

#define HW 4096
#define CCH 256
#define MOFF 432
#define PTOT 32768
#define PDIM 68
#define PIMG (PDIM*PDIM)      // 4624 padded cells per group-plane (2-wide zero border)

typedef unsigned short u16;
typedef __attribute__((ext_vector_type(8))) short short8;
typedef __attribute__((ext_vector_type(8))) unsigned short u16x8;
typedef __attribute__((ext_vector_type(4))) unsigned short u16x4;
typedef __attribute__((ext_vector_type(4))) float f32x4;

__device__ __forceinline__ u16 f2b(float f){
  unsigned int u = __float_as_uint(f);
  unsigned int rounding = 0x7FFFu + ((u >> 16) & 1u);
  return (u16)((u + rounding) >> 16);
}
__device__ __forceinline__ float b2f(u16 s){
  return __uint_as_float(((unsigned int)s) << 16);
}

// ---------------------------------------------------------------------------
// k_prepw: weight prep only (no x transpose). grid 1553:
//  [0,256)    wb_big rows 0..255   = bf16(w1)
//  [256,336)  wb_big rows 688..767 = 0 (N-pad)
//  [336,592)  wb2 = bf16(w2)
//  592        BN fold
//  [593,1121) h1p planar border zero (528 blocks)
//  [1121,1553) wcomb: wb_big row 256+j = bf16(woff[j] . w1); bcomb[j]
// ---------------------------------------------------------------------------
__global__ __launch_bounds__(256) void k_prepw(
    const float* __restrict__ w1, const float* __restrict__ w2,
    const float* __restrict__ woff, const float* __restrict__ b1,
    const float* __restrict__ boff,
    const float* __restrict__ gamma, const float* __restrict__ beta,
    const float* __restrict__ mean, const float* __restrict__ var,
    u16* __restrict__ wb_big, u16* __restrict__ wb2,
    float* __restrict__ bnA, float* __restrict__ bnB,
    float* __restrict__ bcomb, u16* __restrict__ h1p){
  __shared__ float sbuf[512];
  int r = blockIdx.x, t = threadIdx.x;
  if (r < 256) wb_big[r*256 + t] = f2b(w1[r*256 + t]);
  else if (r < 336){ wb_big[(688 + (r - 256)) * 256 + t] = 0; }
  else if (r < 592){ int o = r - 336; wb2[o*256 + t] = f2b(w2[o*256 + t]); }
  else if (r == 592){
    if (t < 256){
      float sc = gamma[t] * rsqrtf(var[t] + 1e-5f);
      bnA[t] = sc;
      bnB[t] = beta[t] - mean[t] * sc;
    }
  } else if (r < 1121){
    int n = (r - 593) * 128 + (t >> 1);   // border cell index
    int seg = t & 1;
    int plane = n / 528, m = n % 528;
    int row, col;
    if (m < 136){ row = m / 68; col = m % 68; }
    else if (m < 272){ int mm = m - 136; row = 66 + mm / 68; col = mm % 68; }
    else { int mm = m - 272; row = 2 + (mm >> 2); int c4 = mm & 3; col = (c4 & 1) + 66 * (c4 >> 1); }
    u16x8 z = {};
    *reinterpret_cast<u16x8*>(&h1p[((size_t)plane * PIMG + row * PDIM + col) * 16 + seg * 8]) = z;
  } else {
    float* wr_ = sbuf;
    float* pb  = sbuf + 256;
    const int j = r - 1121;
    wr_[t] = woff[j * 256 + t];
    __syncthreads();
    float s = 0.f;
    #pragma unroll 8
    for (int m = 0; m < 256; ++m) s += wr_[m] * w1[m * 256 + t];
    wb_big[(256 + j) * 256 + t] = f2b(s);
    pb[t] = wr_[t] * b1[t];
    __syncthreads();
    if (t == 0){
      float bs = boff[j];
      for (int m = 0; m < 256; ++m) bs += pb[m];
      bcomb[j] = bs;
    }
  }
}

// ---------------------------------------------------------------------------
// k_mega: [h1 | om] = x * wb_big^T with x read DIRECTLY (no xT pass).
// 512 blocks; each owns a 64-px stripe. Phase 0: load x stripe [256c][64p]
// fp32, transpose+cvt ONCE into persistent A_lds [64p][260] bf16. Then 6
// o-chunks (128-wide, BK=64, 64 MFMA/barrier-pair) vs resident A.
// cols 0-255 -> h1p planar (+b1); cols 256-687 -> om (+bcomb), guard 432.
// ---------------------------------------------------------------------------
__global__ __launch_bounds__(256, 3) void k_mega(const float* __restrict__ x,
    const u16* __restrict__ Bw, const float* __restrict__ b1,
    const float* __restrict__ bcomb, u16* __restrict__ h1p,
    u16* __restrict__ om){
  __shared__ __align__(16) u16 A_lds[64 * 260];   // 33280 B, persistent
  __shared__ __align__(16) u16 scr[9216];         // 18432 B: Bs [128][72] / C_l [64][136]

  const int t = threadIdx.x;
  const int tm = blockIdx.x * 64;
  const int b = tm >> 12, ploc = tm & 4095;
  const int lane = t & 63;
  const int wid = t >> 6;
  const int wr = wid >> 1, wc = wid & 1;      // 2x2 waves; wave tile 32p x 64o

  // ---- Phase 0: x stripe -> A_lds (transpose + bf16), once ----
  {
    const float* xs = x + (size_t)b * 256 * HW + ploc;
    #pragma unroll
    for (int it = 0; it < 16; ++it){
      int c = it * 16 + (t >> 4);
      int p4 = (t & 15) * 4;
      float4 v = *reinterpret_cast<const float4*>(&xs[(size_t)c * HW + p4]);
      A_lds[(p4 + 0) * 260 + c] = f2b(v.x);
      A_lds[(p4 + 1) * 260 + c] = f2b(v.y);
      A_lds[(p4 + 2) * 260 + c] = f2b(v.z);
      A_lds[(p4 + 3) * 260 + c] = f2b(v.w);
    }
  }
  __syncthreads();

  // ---- 6 o-chunks of 128 ----
  for (int oc6 = 0; oc6 < 6; ++oc6){
    const int tn = oc6 * 128;
    f32x4 acc[2][4] = {};

    for (int kc = 0; kc < 256; kc += 64){
      #pragma unroll
      for (int i = 0; i < 4; ++i){
        int idx = t + i * 256;
        int row = idx >> 3, cq = idx & 7;
        *reinterpret_cast<u16x8*>(&scr[row * 72 + cq * 8]) =
          *reinterpret_cast<const u16x8*>(&Bw[(size_t)(tn + row) * 256 + kc + cq * 8]);
      }
      __syncthreads();
      #pragma unroll
      for (int kk = 0; kk < 2; ++kk){
        short8 af[2], bf[4];
        #pragma unroll
        for (int m = 0; m < 2; ++m)
          af[m] = *reinterpret_cast<const short8*>(
            &A_lds[(wr * 32 + m * 16 + (lane & 15)) * 260 + kc + kk * 32 + (lane >> 4) * 8]);
        #pragma unroll
        for (int n = 0; n < 4; ++n)
          bf[n] = *reinterpret_cast<const short8*>(
            &scr[(wc * 64 + n * 16 + (lane & 15)) * 72 + kk * 32 + (lane >> 4) * 8]);
        #pragma unroll
        for (int m = 0; m < 2; ++m)
          #pragma unroll
          for (int n = 0; n < 4; ++n)
            acc[m][n] = __builtin_amdgcn_mfma_f32_16x16x32_bf16(af[m], bf[n], acc[m][n], 0, 0, 0);
      }
      __syncthreads();
    }

    // epilogue: acc -> C_l (overlay on scr) -> global
    constexpr int CP = 136;
    u16* C_l = scr;
    #pragma unroll
    for (int n = 0; n < 4; ++n){
      int col = wc * 64 + n * 16 + (lane & 15);
      int o = tn + col;
      float bi = (o < 256) ? b1[o] : ((o - 256 < MOFF) ? bcomb[o - 256] : 0.f);
      #pragma unroll
      for (int m = 0; m < 2; ++m){
        int r0 = wr * 32 + m * 16 + ((lane >> 4) << 2);
        #pragma unroll
        for (int j = 0; j < 4; ++j)
          C_l[(r0 + j) * CP + col] = f2b(acc[m][n][j] + bi);
      }
    }
    __syncthreads();
    #pragma unroll
    for (int pass = 0; pass < 4; ++pass){
      int row = pass * 16 + (t >> 4);
      int sg = t & 15;
      int oc = tn + sg * 8;
      int p = tm + row;
      if (tn < 256){
        int bb = p >> 12, ii = (p >> 6) & 63, jj = p & 63;
        size_t dst = ((size_t)(bb * 16 + (oc >> 4)) * PIMG + (ii + 2) * PDIM + jj + 2) * 16 + (oc & 15);
        *reinterpret_cast<u16x8*>(&h1p[dst]) =
          *reinterpret_cast<const u16x8*>(&C_l[row * CP + sg * 8]);
      } else {
        int occ = oc - 256;
        if (occ + 8 <= MOFF)
          *reinterpret_cast<u16x8*>(&om[(size_t)p * MOFF + occ]) =
            *reinterpret_cast<const u16x8*>(&C_l[row * CP + sg * 8]);
      }
    }
    __syncthreads();
  }
}

// ---------------------------------------------------------------------------
// k_sample: 4 px/block, 4-lane units per (px,g), tap-record precompute (R9).
// ---------------------------------------------------------------------------
__global__ __launch_bounds__(256, 4) void k_sample(const u16* __restrict__ h1p,
    const u16* __restrict__ om, u16* __restrict__ ydcn){
  __shared__ float oms[4 * MOFF];        // 6912 B
  __shared__ float recs[5 * 576];        // 11520 B SoA: c00|c01|c10|c11|addr
  const int t = threadIdx.x;
  const int pblk = blockIdx.x * 4;
  if (t < 216){
    u16x8 v = *reinterpret_cast<const u16x8*>(&om[(size_t)pblk * MOFF + t * 8]);
    float4 lo, hi;
    lo.x = b2f(v[0]); lo.y = b2f(v[1]); lo.z = b2f(v[2]); lo.w = b2f(v[3]);
    hi.x = b2f(v[4]); hi.y = b2f(v[5]); hi.z = b2f(v[6]); hi.w = b2f(v[7]);
    *reinterpret_cast<float4*>(&oms[t * 8]) = lo;
    *reinterpret_cast<float4*>(&oms[t * 8 + 4]) = hi;
  }
  __syncthreads();

  #pragma unroll
  for (int i = 0; i < 3; ++i){
    int r = t + i * 256;
    if (i < 2 || r < 576){
      int px = r / 144, rm = r % 144;
      int g = rm / 9, k = rm % 9;
      const float* ob = &oms[px * MOFF + g * 27];
      float oh = ob[2 * k], ow = ob[2 * k + 1], m = ob[18 + k];
      int hw = (pblk + px) & 4095;
      float ph = (float)((hw >> 6) + k / 3 - 1) + oh;
      float pw = (float)((hw & 63) + k % 3 - 1) + ow;
      float h0f = floorf(ph), w0f = floorf(pw);
      float ah = ph - h0f, aw = pw - w0f;
      int h0 = (int)h0f, w0 = (int)w0f;
      int hc = min(max(h0, -2), 64) + 2;
      int wc = min(max(w0, -2), 64) + 2;
      float mh1 = m * ah, mh0 = m - mh1;
      float c01 = mh0 * aw, c00 = mh0 - c01;
      float c11 = mh1 * aw, c10 = mh1 - c11;
      recs[r]            = c00;
      recs[576 + r]      = c01;
      recs[1152 + r]     = c10;
      recs[1728 + r]     = c11;
      recs[2304 + r]     = __uint_as_float((unsigned)((hc * PDIM + wc) << 5));
    }
  }
  __syncthreads();

  const int px = t >> 6;
  const int g = (t >> 2) & 15;
  const int q = t & 3;
  const int p = pblk + px;
  const int b = p >> 12;
  const int xsel = q >> 1;
  const u16* lanebase = h1p + (size_t)(b * 16 + g) * PIMG * 16 + q * 8;
  const int ri = px * 144 + g * 9;
  const float* ctp = &recs[xsel * 576 + ri];
  const float* cbp = &recs[1152 + xsel * 576 + ri];
  const float* adp = &recs[2304 + ri];

  float acc[8] = {};
  #pragma unroll
  for (int k = 0; k < 9; ++k){
    float ct = ctp[k];
    float cb = cbp[k];
    unsigned off = __float_as_uint(adp[k]);
    const u16* c0 = (const u16*)((const char*)lanebase + off);
    u16x8 tv = *reinterpret_cast<const u16x8*>(c0);
    u16x8 bv = *reinterpret_cast<const u16x8*>(c0 + PDIM * 16);
    #pragma unroll
    for (int j = 0; j < 8; ++j)
      acc[j] += ct * b2f(tv[j]) + cb * b2f(bv[j]);
  }
  #pragma unroll
  for (int j = 0; j < 8; ++j)
    acc[j] += __shfl_xor(acc[j], 2, 64);
  if (q < 2){
    u16x8 o8;
    #pragma unroll
    for (int j = 0; j < 8; ++j) o8[j] = f2b(acc[j]);
    *reinterpret_cast<u16x8*>(&ydcn[(size_t)p * 256 + g * 16 + q * 8]) = o8;
  }
}

// ---------------------------------------------------------------------------
// k_gemm2: conv2 + BN + SiLU, tile 128x128, out fp32 NCHW.
// ---------------------------------------------------------------------------
__global__ __launch_bounds__(256) void k_gemm2(const u16* __restrict__ A,
    const u16* __restrict__ Bw, const float* __restrict__ bnA,
    const float* __restrict__ bnB, float* __restrict__ out){
  __shared__ __align__(16) u16 smem[(128 + 128) * 40];
  const int t = threadIdx.x;
  const int tm = blockIdx.x * 128;
  const int tn = blockIdx.y * 128;
  const int lane = t & 63;
  const int wid = t >> 6;
  const int wr = wid >> 1, wc = wid & 1;
  constexpr int BOFF = 128 * 40;

  f32x4 acc[4][4] = {};

  for (int kc = 0; kc < 256; kc += 32){
    #pragma unroll
    for (int i = 0; i < 2; ++i){
      int v = t + i * 256;
      int row = v >> 2, cq = v & 3;
      *reinterpret_cast<u16x8*>(&smem[row * 40 + cq * 8]) =
        *reinterpret_cast<const u16x8*>(&A[(size_t)(tm + row) * 256 + kc + cq * 8]);
    }
    #pragma unroll
    for (int i = 0; i < 2; ++i){
      int v = t + i * 256;
      int row = v >> 2, cq = v & 3;
      *reinterpret_cast<u16x8*>(&smem[BOFF + row * 40 + cq * 8]) =
        *reinterpret_cast<const u16x8*>(&Bw[(size_t)(tn + row) * 256 + kc + cq * 8]);
    }
    __syncthreads();
    short8 af[4], bf[4];
    #pragma unroll
    for (int m = 0; m < 4; ++m)
      af[m] = *reinterpret_cast<const short8*>(
        &smem[(wr * 64 + m * 16 + (lane & 15)) * 40 + (lane >> 4) * 8]);
    #pragma unroll
    for (int n = 0; n < 4; ++n)
      bf[n] = *reinterpret_cast<const short8*>(
        &smem[BOFF + (wc * 64 + n * 16 + (lane & 15)) * 40 + (lane >> 4) * 8]);
    #pragma unroll
    for (int m = 0; m < 4; ++m)
      #pragma unroll
      for (int n = 0; n < 4; ++n)
        acc[m][n] = __builtin_amdgcn_mfma_f32_16x16x32_bf16(af[m], bf[n], acc[m][n], 0, 0, 0);
    __syncthreads();
  }

  const int bimg = tm >> 12;
  const int ploc = tm & 4095;
  #pragma unroll
  for (int n = 0; n < 4; ++n){
    int o = tn + wc * 64 + n * 16 + (lane & 15);
    float sA = bnA[o], sB = bnB[o];
    #pragma unroll
    for (int m = 0; m < 4; ++m){
      int prow = wr * 64 + m * 16 + ((lane >> 4) << 2);
      f32x4 st;
      #pragma unroll
      for (int j = 0; j < 4; ++j){
        float y = acc[m][n][j] * sA + sB;
        st[j] = y / (1.f + expf(-y));
      }
      *reinterpret_cast<f32x4*>(&out[((size_t)(bimg * 256 + o)) * HW + ploc + prow]) = st;
    }
  }
}

extern "C" void kernel_launch(void* const* d_in, const int* in_sizes, int n_in,
                              void* d_out, int out_size, void* d_ws, size_t ws_size,
                              hipStream_t stream) {
  const float* x     = (const float*)d_in[0];
  const float* w1    = (const float*)d_in[1];
  const float* b1    = (const float*)d_in[2];
  const float* woff  = (const float*)d_in[3];
  const float* boff  = (const float*)d_in[4];
  const float* w2    = (const float*)d_in[5];
  const float* gamma = (const float*)d_in[6];
  const float* beta  = (const float*)d_in[7];
  const float* mean  = (const float*)d_in[8];
  const float* var   = (const float*)d_in[9];
  float* out = (float*)d_out;
  (void)in_sizes; (void)n_in; (void)out_size; (void)ws_size;

  u16* h1p    = (u16*)d_ws;                               // 128 planes * 4624 * 32B = 18.9 MB
  u16* om     = h1p + (size_t)128 * PIMG * 16;            // 32768*432 = 28.3 MB
  u16* ydcn   = om + (size_t)PTOT * MOFF;                 // 32768*256 = 16.8 MB
  u16* wb_big = ydcn + (size_t)PTOT * CCH;                // 768*256 bf16
  u16* wb2    = wb_big + 768 * 256;                       // 256*256
  float* bnA  = (float*)(wb2 + 256 * 256);
  float* bnB  = bnA + 256;
  float* bcomb = bnB + 256;                               // 432 f32

  dim3 blk(256);
  k_prepw<<<dim3(1553), blk, 0, stream>>>(w1, w2, woff, b1, boff,
                                          gamma, beta, mean, var,
                                          wb_big, wb2, bnA, bnB, bcomb, h1p);
  k_mega<<<dim3(512), blk, 0, stream>>>(x, wb_big, b1, bcomb, h1p, om);
  k_sample<<<dim3(PTOT / 4), blk, 0, stream>>>(h1p, om, ydcn);
  k_gemm2<<<dim3(PTOT / 128, 2), blk, 0, stream>>>(ydcn, wb2, bnA, bnB, out);
}